// Round 6
// baseline (85177.881 us; speedup 1.0000x reference)
//
#include <hip/hip_runtime.h>
#include <stdint.h>

#define T_   512
#define H_   256
#define OUTD 128
#define XD   4            // x-ring depth (L0 -> L1), slack 3
// own-h rings: DEPTH=2 (slot = s&1) — measured best (R2 vs R3/R4)

typedef unsigned long long u64;
typedef __attribute__((ext_vector_type(8))) short s8v;
typedef __attribute__((ext_vector_type(4))) float f4v;

#define AGL32(p)   __hip_atomic_load((p),  __ATOMIC_RELAXED, __HIP_MEMORY_SCOPE_AGENT)
#define AGS32(p,v) __hip_atomic_store((p), (v), __ATOMIC_RELAXED, __HIP_MEMORY_SCOPE_AGENT)

// Fast path (pair co-located on one XCD, runtime-verified): publish = WG-scope
// atomic store (write-through L1, lands in the shared XCD L2); poll = WG-scope
// atomic fetch_add(0) — an RMW must read latest-in-modification-order and
// executes at the TCC (L2), never in L1, so it observes same-L2 stores. This
// is guaranteed by RMW semantics (unlike R5's plain sc0 loads, which could be
// served stale — measured failure). Fallback: agent-scope atomics (R2 path).
__device__ __forceinline__ u64 probe64(u64* p, bool fast) {
  if (fast) return __hip_atomic_fetch_add(p, 0ull, __ATOMIC_RELAXED, __HIP_MEMORY_SCOPE_WORKGROUP);
  return __hip_atomic_load(p, __ATOMIC_RELAXED, __HIP_MEMORY_SCOPE_AGENT);
}
__device__ __forceinline__ void pub64(u64* p, u64 v, bool fast) {
  if (fast) __hip_atomic_store(p, v, __ATOMIC_RELAXED, __HIP_MEMORY_SCOPE_WORKGROUP);
  else      __hip_atomic_store(p, v, __ATOMIC_RELAXED, __HIP_MEMORY_SCOPE_AGENT);
}
__device__ __forceinline__ unsigned probe32(unsigned* p, bool fast) {
  if (fast) return __hip_atomic_fetch_add(p, 0u, __ATOMIC_RELAXED, __HIP_MEMORY_SCOPE_WORKGROUP);
  return __hip_atomic_load(p, __ATOMIC_RELAXED, __HIP_MEMORY_SCOPE_AGENT);
}
__device__ __forceinline__ void pub32(unsigned* p, unsigned v, bool fast) {
  if (fast) __hip_atomic_store(p, v, __ATOMIC_RELAXED, __HIP_MEMORY_SCOPE_WORKGROUP);
  else      __hip_atomic_store(p, v, __ATOMIC_RELAXED, __HIP_MEMORY_SCOPE_AGENT);
}

__device__ __forceinline__ f4v mfma16x16x32(s8v a, s8v b, f4v c) {
  return __builtin_amdgcn_mfma_f32_16x16x32_bf16(a, b, c, 0, 0, 0);
}

// fp32 -> bf16 hi (truncate) + bf16 lo (RN of remainder)
__device__ __forceinline__ void split_bf16(float f, short &hi, short &lo) {
  unsigned u  = __float_as_uint(f);
  unsigned uh = u & 0xffff0000u;
  hi = (short)(uh >> 16);
  float r = f - __uint_as_float(uh);
  unsigned ur = __float_as_uint(r);
  lo = (short)((ur + 0x7fffu + ((ur >> 16) & 1u)) >> 16);
}
__device__ __forceinline__ unsigned pack_hilo(float f) {
  short hi, lo; split_bf16(f, hi, lo);
  return ((unsigned)(unsigned short)hi << 16) | (unsigned)(unsigned short)lo;
}
__device__ __forceinline__ float sig_(float x) { return 1.f / (1.f + __expf(-x)); }
__device__ __forceinline__ float th_(float x)  { float e = __expf(2.f * x); return 1.f - 2.f / (e + 1.f); }

struct SMem {
  short xhi[16][264], xlo[16][264];
  short hhi[16][264], hlo[16][264];
  float gl[4][16][17];
  float bias[64];
  float rfminf;          // (reuse as generic broadcast)
  unsigned rfmin;
  unsigned l2flag;
};

#define TOKEN 0xC0FFEE1234567890ull

// Exchange entry = u64 (tag<<32 | bf16hi<<16 | bf16lo), tag = step+1. Own-h
// ring: 2 slots, safe by induction (observing all tags s-1 implies everyone
// consumed s-2). X-ring (L0->L1): XD=4 slots, guarded by per-member monotonic
// rflag back-pressure checked lazily with slack XD-1. Tag equality rejects
// ring reuse and the 0xAA poison.
template <int LAYER>
__device__ __forceinline__ void lstm_body(
    SMem* sm,
    const float* __restrict__ xin,
    const float* __restrict__ Wih, const float* __restrict__ Whh,
    const float* __restrict__ bih, const float* __restrict__ bhh,
    u64* xr,            // pair's x-ring (L0 writes, L1 reads)
    u64* own,           // own-h ring (this group-layer)
    unsigned* rflag, unsigned* xflag, u64* tflag, float* h1l,
    int p, int mem)
{
  constexpr int KX  = (LAYER == 0) ? 128 : 256;
  constexpr int NKX = KX / 32;
  const int tid = threadIdx.x;
  const int w = tid >> 6, lane = tid & 63, n = lane & 15, q = lane >> 4;
  const int bb = tid >> 4, uu = tid & 15;
  const int B0 = p * 16, U0 = mem * 16;
  const int myidx = LAYER * 16 + mem;

  unsigned* xfA = xflag + p * 64;        // phase A: XCC ids
  unsigned* xfV = xfA + 32;              // phase C: verdicts
  u64*      tf  = tflag + p * 32;        // phase B: fast-primitive tokens

  // ---- handshake A: publish my XCD id (agent scope, one-time) ----
  if (tid == 0) {
    unsigned xcc;
    asm volatile("s_getreg_b32 %0, hwreg(HW_REG_XCC_ID)" : "=s"(xcc));
    AGS32(&xfA[myidx], 0xB0000000u | (xcc & 0xffu));
  }

  // ---- weight slice -> register B-fragments (bf16 hi/lo), once ----
  s8v wxh[NKX], wxl[NKX], whhh[8], whhl[8];
  {
    const int row = w * 256 + U0 + n;
    #pragma unroll
    for (int kf = 0; kf < NKX; ++kf) {
      s8v vh, vl;
      #pragma unroll
      for (int j = 0; j < 8; ++j) { short hi, lo; split_bf16(Wih[row * KX + kf * 32 + q * 8 + j], hi, lo); vh[j] = hi; vl[j] = lo; }
      wxh[kf] = vh; wxl[kf] = vl;
    }
    #pragma unroll
    for (int kf = 0; kf < 8; ++kf) {
      s8v vh, vl;
      #pragma unroll
      for (int j = 0; j < 8; ++j) { short hi, lo; split_bf16(Whh[row * 256 + kf * 32 + q * 8 + j], hi, lo); vh[j] = hi; vl[j] = lo; }
      whhh[kf] = vh; whhl[kf] = vl;
    }
  }
  if (tid < 64) {
    int gate = tid >> 4, u = tid & 15;
    int grow = gate * 256 + U0 + u;
    sm->bias[tid] = bih[grow] + bhh[grow];
  }

  // ---- handshake B/C: smoke-test fast primitives, agree uniformly ----
  if (tid == 0) {
    // A-gather: all 32 present and same XCD?
    bool colo = false;
    {
      int it = 0;
      for (;;) {
        bool all = true, uni = true; unsigned first = 0;
        for (int i = 0; i < 32; ++i) {
          unsigned v = AGL32(&xfA[i]);
          if ((v >> 28) != 0xBu) { all = false; break; }
          if (i == 0) first = v; else uni &= (v == first);
        }
        if (all) { colo = uni; break; }
        if (++it >= 200000) break;
        __builtin_amdgcn_s_sleep(8);
      }
    }
    // B: exercise the actual fast publish/probe primitives
    bool okf = false;
    if (colo) {
      pub64(&tf[myidx], TOKEN, true);
      int it = 0;
      for (;;) {
        bool all = true;
        for (int i = 0; i < 32; ++i)
          if (probe64(&tf[i], true) != TOKEN) { all = false; break; }
        if (all) { okf = true; break; }
        if (++it >= 50000) break;
        __builtin_amdgcn_s_sleep(2);
      }
    }
    // C: publish verdict (agent), require unanimous pass
    AGS32(&xfV[myidx], 0xD0000000u | (okf ? 1u : 0u));
    unsigned l2 = 0;
    {
      int it = 0;
      for (;;) {
        bool all = true, good = true;
        for (int i = 0; i < 32; ++i) {
          unsigned v = AGL32(&xfV[i]);
          if ((v >> 28) != 0xDu) { all = false; break; }
          good &= (v & 1u);
        }
        if (all) { l2 = good ? 1u : 0u; break; }
        if (++it >= 400000) { l2 = 0; break; }
        __builtin_amdgcn_s_sleep(8);
      }
    }
    sm->l2flag = l2;
  }
  __syncthreads();
  const bool l2m = (sm->l2flag != 0u);

  unsigned* rfg    = rflag + p * 256;           // member m's flag at rfg[m*16]
  unsigned* rfself = rfg + mem * 16;

  float c = 0.f;
  unsigned rf_cached = 0;

  for (int s = 0; s < T_; ++s) {
    // ---- layer0: fp32 x loads (plain cached; overlap the h poll) ----
    float xv[8];
    if (LAYER == 0) {
      const float* px = xin + ((size_t)(B0 + bb) * T_ + s) * 128 + uu * 8;
      float4 v0 = *(const float4*)px, v1 = *(const float4*)(px + 4);
      xv[0] = v0.x; xv[1] = v0.y; xv[2] = v0.z; xv[3] = v0.w;
      xv[4] = v1.x; xv[5] = v1.y; xv[6] = v1.z; xv[7] = v1.w;
    }

    // ---- poll phase ----
    if (LAYER == 1) {
      u64* tbx = xr + (size_t)(s & (XD - 1)) * 4096;
      const unsigned xtag = (unsigned)(s + 1);
      u64 xv64[16], hv64[16];
      if (s > 0) {
        u64* tbh = own + (size_t)((s - 1) & 1) * 4096;
        const unsigned htag = (unsigned)s;
        int it = 0;
        for (;;) {
          #pragma unroll
          for (int i = 0; i < 16; ++i) xv64[i] = probe64(&tbx[i * 256 + tid], l2m);
          #pragma unroll
          for (int i = 0; i < 16; ++i) hv64[i] = probe64(&tbh[i * 256 + tid], l2m);
          bool ok = true;
          #pragma unroll
          for (int i = 0; i < 16; ++i) ok &= ((unsigned)(xv64[i] >> 32) == xtag);
          #pragma unroll
          for (int i = 0; i < 16; ++i) ok &= ((unsigned)(hv64[i] >> 32) == htag);
          if (ok) break;
          if (++it >= 20000) break;          // no-hang safety
          __builtin_amdgcn_s_sleep(1);
        }
        #pragma unroll
        for (int i = 0; i < 16; ++i) {
          unsigned d = (unsigned)hv64[i];
          sm->hhi[i][tid] = (short)(d >> 16);
          sm->hlo[i][tid] = (short)(d & 0xffffu);
        }
      } else {
        int it = 0;
        for (;;) {
          #pragma unroll
          for (int i = 0; i < 16; ++i) xv64[i] = probe64(&tbx[i * 256 + tid], l2m);
          bool ok = true;
          #pragma unroll
          for (int i = 0; i < 16; ++i) ok &= ((unsigned)(xv64[i] >> 32) == xtag);
          if (ok) break;
          if (++it >= 20000) break;
          __builtin_amdgcn_s_sleep(1);
        }
        #pragma unroll
        for (int i = 0; i < 16; ++i) { sm->hhi[i][tid] = 0; sm->hlo[i][tid] = 0; }
      }
      #pragma unroll
      for (int i = 0; i < 16; ++i) {
        unsigned d = (unsigned)xv64[i];
        sm->xhi[i][tid] = (short)(d >> 16);
        sm->xlo[i][tid] = (short)(d & 0xffffu);
      }
    } else {
      if (s > 0) {
        u64* tbh = own + (size_t)((s - 1) & 1) * 4096;
        const unsigned htag = (unsigned)s;
        u64 hv64[16]; int it = 0;
        for (;;) {
          #pragma unroll
          for (int i = 0; i < 16; ++i) hv64[i] = probe64(&tbh[i * 256 + tid], l2m);
          bool ok = true;
          #pragma unroll
          for (int i = 0; i < 16; ++i) ok &= ((unsigned)(hv64[i] >> 32) == htag);
          if (ok) break;
          if (++it >= 20000) break;
          __builtin_amdgcn_s_sleep(1);
        }
        #pragma unroll
        for (int i = 0; i < 16; ++i) {
          unsigned d = (unsigned)hv64[i];
          sm->hhi[i][tid] = (short)(d >> 16);
          sm->hlo[i][tid] = (short)(d & 0xffffu);
        }
      } else {
        #pragma unroll
        for (int i = 0; i < 16; ++i) { sm->hhi[i][tid] = 0; sm->hlo[i][tid] = 0; }
      }
      // stage fp32 x as bf16 hi/lo
      s8v vh, vl;
      #pragma unroll
      for (int j = 0; j < 8; ++j) { short hi, lo; split_bf16(xv[j], hi, lo); vh[j] = hi; vl[j] = lo; }
      *(s8v*)&sm->xhi[bb][uu * 8] = vh;
      *(s8v*)&sm->xlo[bb][uu * 8] = vl;
    }
    __syncthreads();

    // layer1: publish read-progress (all threads' loads done at the barrier)
    if (LAYER == 1 && tid == 0)
      pub32(rfself, (unsigned)(s + 1), l2m);

    // ---- bf16x3 MFMA: hi*hi + lo*hi + hi*lo chains ----
    f4v a0 = {0.f, 0.f, 0.f, 0.f}, a1 = a0, a2 = a0;
    #pragma unroll
    for (int kf = 0; kf < NKX; ++kf) {
      s8v ah = *(const s8v*)&sm->xhi[n][kf * 32 + q * 8];
      s8v al = *(const s8v*)&sm->xlo[n][kf * 32 + q * 8];
      a0 = mfma16x16x32(ah, wxh[kf], a0);
      a1 = mfma16x16x32(al, wxh[kf], a1);
      a2 = mfma16x16x32(ah, wxl[kf], a2);
    }
    #pragma unroll
    for (int kf = 0; kf < 8; ++kf) {
      s8v ah = *(const s8v*)&sm->hhi[n][kf * 32 + q * 8];
      s8v al = *(const s8v*)&sm->hlo[n][kf * 32 + q * 8];
      a0 = mfma16x16x32(ah, whhh[kf], a0);
      a1 = mfma16x16x32(al, whhh[kf], a1);
      a2 = mfma16x16x32(ah, whhl[kf], a2);
    }
    f4v D = a0 + (a1 + a2);
    #pragma unroll
    for (int r = 0; r < 4; ++r) sm->gl[w][q * 4 + r][n] = D[r];

    // ---- layer0: lazy back-pressure for x-ring slot s%XD (holds step s-XD;
    //      L1 must have consumed it: rflag >= s-XD+1). Wave 0 polls while
    //      waves 1-3 wait at the barrier; rare thanks to XD-1 slack. ----
    bool polled = false;
    if (LAYER == 0 && s >= XD) {
      const unsigned tgt = (unsigned)(s - XD + 1);
      polled = (rf_cached < tgt);
      if (polled && w == 0) {
        unsigned mn; int it = 0;
        for (;;) {
          unsigned v = (lane < 16) ? probe32(&rfg[lane * 16], l2m) : 0xffffffffu;
          mn = v;
          #pragma unroll
          for (int off = 8; off; off >>= 1) {
            unsigned o = __shfl_xor(mn, off, 16);
            mn = (o < mn) ? o : mn;
          }
          if (mn >= tgt) break;
          if (++it >= 20000) break;
          __builtin_amdgcn_s_sleep(1);
        }
        if (lane == 0) sm->rfmin = mn;
      }
    }
    __syncthreads();
    if (polled) rf_cached = sm->rfmin;   // uniform decision on all threads

    // ---- activations + state ----
    float pi = sm->gl[0][bb][uu] + sm->bias[uu];
    float pf = sm->gl[1][bb][uu] + sm->bias[16 + uu];
    float pg = sm->gl[2][bb][uu] + sm->bias[32 + uu];
    float po = sm->gl[3][bb][uu] + sm->bias[48 + uu];
    float ig = sig_(pi), fg = sig_(pf), gg = th_(pg), og = sig_(po);
    c = fg * c + ig * gg;
    float h = og * th_(c);

    // ---- publish h: own ring (critical) then x-ring (L0 only) ----
    u64 val = ((u64)(unsigned)(s + 1) << 32) | (u64)pack_hilo(h);
    pub64(&own[(size_t)(s & 1) * 4096 + bb * 256 + U0 + uu], val, l2m);
    if (LAYER == 0)
      pub64(&xr[(size_t)(s & (XD - 1)) * 4096 + bb * 256 + U0 + uu], val, l2m);

    if (LAYER == 1 && s == T_ - 1)
      h1l[(B0 + bb) * H_ + U0 + uu] = h;
  }
}

__global__ __launch_bounds__(256, 2) void lstm_fused(
    const float* __restrict__ x,
    const float* __restrict__ Wih0, const float* __restrict__ Whh0,
    const float* __restrict__ bih0, const float* __restrict__ bhh0,
    const float* __restrict__ Wih1, const float* __restrict__ Whh1,
    const float* __restrict__ bih1, const float* __restrict__ bhh1,
    u64* bxo0, u64* bxo1, u64* bxx,
    unsigned* rflag, unsigned* xflag, u64* tflag, float* h1l)
{
  __shared__ SMem sm;
  const int bid = blockIdx.x;
  // pair p occupies bids with constant bid%8 -> one XCD under round-robin
  // dispatch (heuristic; verified by handshake+smoke test, else fallback).
  const int p  = (bid & 7) * 2 + ((bid >> 3) & 1);
  const int mi = bid >> 4;                       // 0..31: 0-15 L0, 16-31 L1
  u64* xr = bxx + (size_t)p * XD * 4096;
  if (mi < 16) {
    lstm_body<0>(&sm, x, Wih0, Whh0, bih0, bhh0, xr, bxo0 + (size_t)p * 8192,
                 rflag, xflag, tflag, nullptr, p, mi);
  } else {
    lstm_body<1>(&sm, nullptr, Wih1, Whh1, bih1, bhh1, xr, bxo1 + (size_t)p * 8192,
                 rflag, xflag, tflag, h1l, p, mi - 16);
  }
}

__global__ void fc_kernel(const float* __restrict__ h1l, const float* __restrict__ Wfc,
                          float* __restrict__ out) {
  __shared__ float hs[H_];
  const int b = blockIdx.x, o = threadIdx.x;
  hs[o]       = h1l[b * H_ + o];
  hs[o + 128] = h1l[b * H_ + o + 128];
  __syncthreads();
  float acc = 0.f;
  #pragma unroll 8
  for (int u = 0; u < H_; u += 4) {
    float4 wv = *(const float4*)&Wfc[o * H_ + u];
    acc += wv.x * hs[u] + wv.y * hs[u + 1] + wv.z * hs[u + 2] + wv.w * hs[u + 3];
  }
  out[b * OUTD + o] = acc;
}

extern "C" void kernel_launch(void* const* d_in, const int* in_sizes, int n_in,
                              void* d_out, int out_size, void* d_ws, size_t ws_size,
                              hipStream_t stream) {
  const float* x    = (const float*)d_in[0];
  const float* Wih0 = (const float*)d_in[1];
  const float* Whh0 = (const float*)d_in[2];
  const float* bih0 = (const float*)d_in[3];
  const float* bhh0 = (const float*)d_in[4];
  const float* Wih1 = (const float*)d_in[5];
  const float* Whh1 = (const float*)d_in[6];
  const float* bih1 = (const float*)d_in[7];
  const float* bhh1 = (const float*)d_in[8];
  const float* Wfc  = (const float*)d_in[9];

  // ws: bxo0 1MiB | bxo1 1MiB | bxx 2MiB | tflag 4KiB | rflag 16KiB | xflag 4KiB | h1l
  u64*      bxo0  = (u64*)d_ws;                       // 16*2*4096
  u64*      bxo1  = bxo0 + 131072;                    // 16*2*4096
  u64*      bxx   = bxo1 + 131072;                    // 16*XD*4096
  u64*      tflag = bxx + 16 * XD * 4096;             // 16*32 u64
  unsigned* rflag = (unsigned*)(tflag + 512);         // 16*256
  unsigned* xflag = rflag + 4096;                     // 16*64
  float*    h1l   = (float*)(xflag + 1024);           // 256*256

  // tflag/rflag/xflag must start 0 (poison 0xAA.. would spoof >= checks;
  // exchange tags + tokens use equality so poison never matches them).
  hipMemsetAsync(tflag, 0, 512 * 8 + (4096 + 1024) * 4, stream);

  lstm_fused<<<512, 256, 0, stream>>>(x, Wih0, Whh0, bih0, bhh0,
                                      Wih1, Whh1, bih1, bhh1,
                                      bxo0, bxo1, bxx, rflag, xflag, tflag, h1l);
  fc_kernel<<<256, 128, 0, stream>>>(h1l, Wfc, (float*)d_out);
}

// Round 7
// 6123.988 us; speedup vs baseline: 13.9089x; 13.9089x over previous
//
#include <hip/hip_runtime.h>
#include <stdint.h>

#define T_   512
#define H_   256
#define OUTD 128
// rings: DEPTH=2 (slot = s&1), single L0 ring feeds both L0 recurrence and L1 x
// (R2 measured-best skeleton).

typedef unsigned long long u64;
typedef __attribute__((ext_vector_type(8))) short s8v;
typedef __attribute__((ext_vector_type(4))) float f4v;

#define AGL32(p)   __hip_atomic_load((p),  __ATOMIC_RELAXED, __HIP_MEMORY_SCOPE_AGENT)
#define AGS32(p,v) __hip_atomic_store((p), (v), __ATOMIC_RELAXED, __HIP_MEMORY_SCOPE_AGENT)

// Vector-L1 invalidate: subsequent loads on this CU refetch from the XCD L2.
// This + write-through plain stores = the L2-local exchange primitive.
// (R5 proved plain/sc0 loads alone are stale; R6 proved plain stores DO reach
// the shared L2 — RMWs read them correctly but convoy at the TCC, 85 ms.)
__device__ __forceinline__ void l1_inv() {
  asm volatile("buffer_inv" ::: "memory");
}

// fast=true (smoke-tested, same-XCD): plain write-through store / plain load
// (validity via inv-per-round + tag equality). fast=false: agent-scope atomics
// (R2 protocol, coherent anywhere, ~memory-side latency).
__device__ __forceinline__ u64 rd64(const u64* p, bool fast) {
  if (fast) return *(const volatile u64*)p;
  return __hip_atomic_load(p, __ATOMIC_RELAXED, __HIP_MEMORY_SCOPE_AGENT);
}
__device__ __forceinline__ void wr64(u64* p, u64 v, bool fast) {
  if (fast) *(volatile u64*)p = v;
  else __hip_atomic_store(p, v, __ATOMIC_RELAXED, __HIP_MEMORY_SCOPE_AGENT);
}
__device__ __forceinline__ unsigned rd32(const unsigned* p, bool fast) {
  if (fast) return *(const volatile unsigned*)p;
  return __hip_atomic_load(p, __ATOMIC_RELAXED, __HIP_MEMORY_SCOPE_AGENT);
}
__device__ __forceinline__ void wr32(unsigned* p, unsigned v, bool fast) {
  if (fast) *(volatile unsigned*)p = v;
  else __hip_atomic_store(p, v, __ATOMIC_RELAXED, __HIP_MEMORY_SCOPE_AGENT);
}

__device__ __forceinline__ f4v mfma16x16x32(s8v a, s8v b, f4v c) {
  return __builtin_amdgcn_mfma_f32_16x16x32_bf16(a, b, c, 0, 0, 0);
}

// fp32 -> bf16 hi (truncate) + bf16 lo (RN of remainder)
__device__ __forceinline__ void split_bf16(float f, short &hi, short &lo) {
  unsigned u  = __float_as_uint(f);
  unsigned uh = u & 0xffff0000u;
  hi = (short)(uh >> 16);
  float r = f - __uint_as_float(uh);
  unsigned ur = __float_as_uint(r);
  lo = (short)((ur + 0x7fffu + ((ur >> 16) & 1u)) >> 16);
}
__device__ __forceinline__ unsigned pack_hilo(float f) {
  short hi, lo; split_bf16(f, hi, lo);
  return ((unsigned)(unsigned short)hi << 16) | (unsigned)(unsigned short)lo;
}
__device__ __forceinline__ float sig_(float x) { return 1.f / (1.f + __expf(-x)); }
__device__ __forceinline__ float th_(float x)  { float e = __expf(2.f * x); return 1.f - 2.f / (e + 1.f); }

struct SMem {
  short xhi[16][264], xlo[16][264];
  short hhi[16][264], hlo[16][264];
  float gl[4][16][17];
  float bias[64];
  unsigned l2flag;
};

#define TOKEN 0xC0FFEE1234567890ull

// Exchange entry = u64 (tag<<32 | bf16hi<<16 | bf16lo), tag = step+1, 2-slot
// rings. Tag equality rejects ring reuse and 0xAA poison. Own-ring overwrite
// safe by induction (a member at step s observed all tags s => everyone
// consumed step s-2). L1 consumes L0's ring directly as x; L0's overwrite of
// step s-2 is gated on L1 read-progress rflag >= s-1 (monotonic, zeroed).
template <int LAYER>
__device__ __forceinline__ void lstm_body(
    SMem* sm,
    const float* __restrict__ xin,
    const float* __restrict__ Wih, const float* __restrict__ Whh,
    const float* __restrict__ bih, const float* __restrict__ bhh,
    u64* src,           // L0 ring of this pair (L1's x source; == own for L0)
    u64* own,           // this layer-group's ring
    unsigned* rflag, unsigned* xflag, u64* tflag, float* h1l,
    int p, int mem)
{
  constexpr int KX  = (LAYER == 0) ? 128 : 256;
  constexpr int NKX = KX / 32;
  const int tid = threadIdx.x;
  const int w = tid >> 6, lane = tid & 63, n = lane & 15, q = lane >> 4;
  const int bb = tid >> 4, uu = tid & 15;
  const int B0 = p * 16, U0 = mem * 16;
  const int myidx = LAYER * 16 + mem;

  unsigned* xfA = xflag + p * 64;        // phase A: XCC ids
  unsigned* xfV = xfA + 32;              // phase C: verdicts
  u64*      tf  = tflag + p * 32;        // phase B: smoke tokens

  // ---- handshake A: publish my XCD id (agent scope, one-time) ----
  if (tid == 0) {
    unsigned xcc;
    asm volatile("s_getreg_b32 %0, hwreg(HW_REG_XCC_ID)" : "=s"(xcc));
    AGS32(&xfA[myidx], 0xB0000000u | (xcc & 0xffu));
  }

  // ---- weight slice -> register B-fragments (bf16 hi/lo), once ----
  s8v wxh[NKX], wxl[NKX], whhh[8], whhl[8];
  {
    const int row = w * 256 + U0 + n;
    #pragma unroll
    for (int kf = 0; kf < NKX; ++kf) {
      s8v vh, vl;
      #pragma unroll
      for (int j = 0; j < 8; ++j) { short hi, lo; split_bf16(Wih[row * KX + kf * 32 + q * 8 + j], hi, lo); vh[j] = hi; vl[j] = lo; }
      wxh[kf] = vh; wxl[kf] = vl;
    }
    #pragma unroll
    for (int kf = 0; kf < 8; ++kf) {
      s8v vh, vl;
      #pragma unroll
      for (int j = 0; j < 8; ++j) { short hi, lo; split_bf16(Whh[row * 256 + kf * 32 + q * 8 + j], hi, lo); vh[j] = hi; vl[j] = lo; }
      whhh[kf] = vh; whhl[kf] = vl;
    }
  }
  if (tid < 64) {
    int gate = tid >> 4, u = tid & 15;
    int grow = gate * 256 + U0 + u;
    sm->bias[tid] = bih[grow] + bhh[grow];
  }

  // ---- handshake B/C: smoke-test the EXACT fast chain, agree uniformly ----
  if (tid == 0) {
    bool colo = false;
    {
      int it = 0;
      for (;;) {
        bool all = true, uni = true; unsigned first = 0;
        for (int i = 0; i < 32; ++i) {
          unsigned v = AGL32(&xfA[i]);
          if ((v >> 28) != 0xBu) { all = false; break; }
          if (i == 0) first = v; else uni &= (v == first);
        }
        if (all) { colo = uni; break; }
        if (++it >= 200000) break;
        __builtin_amdgcn_s_sleep(8);
      }
    }
    // B: plain store TOKEN; spin {inv; plain-load all 32; equality}
    bool okf = false;
    if (colo) {
      *(volatile u64*)&tf[myidx] = TOKEN;
      int it = 0;
      for (;;) {
        l1_inv();
        bool all = true;
        for (int i = 0; i < 32; ++i)
          if (*(volatile u64*)&tf[i] != TOKEN) { all = false; break; }
        if (all) { okf = true; break; }
        if (++it >= 50000) break;
        __builtin_amdgcn_s_sleep(2);
      }
    }
    // C: agent-scope verdicts, unanimous pass required
    AGS32(&xfV[myidx], 0xD0000000u | (okf ? 1u : 0u));
    unsigned l2 = 0;
    {
      int it = 0;
      for (;;) {
        bool all = true, good = true;
        for (int i = 0; i < 32; ++i) {
          unsigned v = AGL32(&xfV[i]);
          if ((v >> 28) != 0xDu) { all = false; break; }
          good &= (v & 1u);
        }
        if (all) { l2 = good ? 1u : 0u; break; }
        if (++it >= 400000) { l2 = 0; break; }
        __builtin_amdgcn_s_sleep(8);
      }
    }
    sm->l2flag = l2;
  }
  __syncthreads();
  const bool l2m = (sm->l2flag != 0u);

  unsigned* rfg    = rflag + p * 256;           // member m's flag at rfg[m*16]
  unsigned* rfself = rfg + mem * 16;

  float c = 0.f;

  for (int s = 0; s < T_; ++s) {
    // ---- layer0: fp32 x loads (plain cached; in flight across the spin) ----
    float xv[8];
    if (LAYER == 0) {
      const float* px = xin + ((size_t)(B0 + bb) * T_ + s) * 128 + uu * 8;
      float4 v0 = *(const float4*)px, v1 = *(const float4*)(px + 4);
      xv[0] = v0.x; xv[1] = v0.y; xv[2] = v0.z; xv[3] = v0.w;
      xv[4] = v1.x; xv[5] = v1.y; xv[6] = v1.z; xv[7] = v1.w;
    }

    // ---- consume phase: spin {inv (fast); loads; tag-equality} ----
    if (LAYER == 1) {
      const u64* tbx = src + (size_t)(s & 1) * 4096;     // L0 step-s data
      const unsigned xtag = (unsigned)(s + 1);
      u64 xv64[16], hv64[16];
      if (s > 0) {
        const u64* tbh = own + (size_t)((s - 1) & 1) * 4096;
        const unsigned htag = (unsigned)s;
        int it = 0;
        for (;;) {
          if (l2m) l1_inv();
          #pragma unroll
          for (int i = 0; i < 16; ++i) xv64[i] = rd64(&tbx[i * 256 + tid], l2m);
          #pragma unroll
          for (int i = 0; i < 16; ++i) hv64[i] = rd64(&tbh[i * 256 + tid], l2m);
          bool ok = true;
          #pragma unroll
          for (int i = 0; i < 16; ++i) ok &= ((unsigned)(xv64[i] >> 32) == xtag);
          #pragma unroll
          for (int i = 0; i < 16; ++i) ok &= ((unsigned)(hv64[i] >> 32) == htag);
          if (ok) break;
          if (++it >= 20000) break;          // no-hang safety
          __builtin_amdgcn_s_sleep(1);
        }
        #pragma unroll
        for (int i = 0; i < 16; ++i) {
          unsigned d = (unsigned)hv64[i];
          sm->hhi[i][tid] = (short)(d >> 16);
          sm->hlo[i][tid] = (short)(d & 0xffffu);
        }
      } else {
        int it = 0;
        for (;;) {
          if (l2m) l1_inv();
          #pragma unroll
          for (int i = 0; i < 16; ++i) xv64[i] = rd64(&tbx[i * 256 + tid], l2m);
          bool ok = true;
          #pragma unroll
          for (int i = 0; i < 16; ++i) ok &= ((unsigned)(xv64[i] >> 32) == xtag);
          if (ok) break;
          if (++it >= 20000) break;
          __builtin_amdgcn_s_sleep(1);
        }
        #pragma unroll
        for (int i = 0; i < 16; ++i) { sm->hhi[i][tid] = 0; sm->hlo[i][tid] = 0; }
      }
      #pragma unroll
      for (int i = 0; i < 16; ++i) {
        unsigned d = (unsigned)xv64[i];
        sm->xhi[i][tid] = (short)(d >> 16);
        sm->xlo[i][tid] = (short)(d & 0xffffu);
      }
    } else {
      if (s > 0) {
        const u64* tbh = own + (size_t)((s - 1) & 1) * 4096;
        const unsigned htag = (unsigned)s;
        u64 hv64[16]; int it = 0;
        for (;;) {
          if (l2m) l1_inv();
          #pragma unroll
          for (int i = 0; i < 16; ++i) hv64[i] = rd64(&tbh[i * 256 + tid], l2m);
          bool ok = true;
          #pragma unroll
          for (int i = 0; i < 16; ++i) ok &= ((unsigned)(hv64[i] >> 32) == htag);
          if (ok) break;
          if (++it >= 20000) break;
          __builtin_amdgcn_s_sleep(1);
        }
        #pragma unroll
        for (int i = 0; i < 16; ++i) {
          unsigned d = (unsigned)hv64[i];
          sm->hhi[i][tid] = (short)(d >> 16);
          sm->hlo[i][tid] = (short)(d & 0xffffu);
        }
      } else {
        #pragma unroll
        for (int i = 0; i < 16; ++i) { sm->hhi[i][tid] = 0; sm->hlo[i][tid] = 0; }
      }
      // stage fp32 x as bf16 hi/lo
      s8v vh, vl;
      #pragma unroll
      for (int j = 0; j < 8; ++j) { short hi, lo; split_bf16(xv[j], hi, lo); vh[j] = hi; vl[j] = lo; }
      *(s8v*)&sm->xhi[bb][uu * 8] = vh;
      *(s8v*)&sm->xlo[bb][uu * 8] = vl;
    }
    __syncthreads();

    // layer1: publish read-progress (all threads' loads done at the barrier)
    if (LAYER == 1 && tid == 0)
      wr32(rfself, (unsigned)(s + 1), l2m);

    // ---- bf16x3 MFMA: hi*hi + lo*hi + hi*lo chains ----
    f4v a0 = {0.f, 0.f, 0.f, 0.f}, a1 = a0, a2 = a0;
    #pragma unroll
    for (int kf = 0; kf < NKX; ++kf) {
      s8v ah = *(const s8v*)&sm->xhi[n][kf * 32 + q * 8];
      s8v al = *(const s8v*)&sm->xlo[n][kf * 32 + q * 8];
      a0 = mfma16x16x32(ah, wxh[kf], a0);
      a1 = mfma16x16x32(al, wxh[kf], a1);
      a2 = mfma16x16x32(ah, wxl[kf], a2);
    }
    #pragma unroll
    for (int kf = 0; kf < 8; ++kf) {
      s8v ah = *(const s8v*)&sm->hhi[n][kf * 32 + q * 8];
      s8v al = *(const s8v*)&sm->hlo[n][kf * 32 + q * 8];
      a0 = mfma16x16x32(ah, whhh[kf], a0);
      a1 = mfma16x16x32(al, whhh[kf], a1);
      a2 = mfma16x16x32(ah, whhl[kf], a2);
    }
    f4v D = a0 + (a1 + a2);
    #pragma unroll
    for (int r = 0; r < 4; ++r) sm->gl[w][q * 4 + r][n] = D[r];

    // ---- layer0: back-pressure before overwriting slot s&1 (holds step s-2;
    //      L1 must have consumed it: rflag >= s-1). Wave 0 polls while waves
    //      1-3 wait at the barrier. ----
    if (LAYER == 0 && s >= 2 && w == 0) {
      const unsigned tgt = (unsigned)(s - 1); int it = 0;
      for (;;) {
        if (l2m) l1_inv();
        unsigned v = (lane < 16) ? rd32(&rfg[lane * 16], l2m) : tgt;
        if (__all((int)(v >= tgt))) break;
        if (++it >= 20000) break;
        __builtin_amdgcn_s_sleep(1);
      }
    }
    __syncthreads();

    // ---- activations + state ----
    float pi = sm->gl[0][bb][uu] + sm->bias[uu];
    float pf = sm->gl[1][bb][uu] + sm->bias[16 + uu];
    float pg = sm->gl[2][bb][uu] + sm->bias[32 + uu];
    float po = sm->gl[3][bb][uu] + sm->bias[48 + uu];
    float ig = sig_(pi), fg = sig_(pf), gg = th_(pg), og = sig_(po);
    c = fg * c + ig * gg;
    float h = og * th_(c);

    // ---- publish h (tagged, fire-and-forget write-through) ----
    u64 val = ((u64)(unsigned)(s + 1) << 32) | (u64)pack_hilo(h);
    wr64(&own[(size_t)(s & 1) * 4096 + bb * 256 + U0 + uu], val, l2m);

    if (LAYER == 1 && s == T_ - 1)
      h1l[(B0 + bb) * H_ + U0 + uu] = h;
  }
}

__global__ __launch_bounds__(256, 2) void lstm_fused(
    const float* __restrict__ x,
    const float* __restrict__ Wih0, const float* __restrict__ Whh0,
    const float* __restrict__ bih0, const float* __restrict__ bhh0,
    const float* __restrict__ Wih1, const float* __restrict__ Whh1,
    const float* __restrict__ bih1, const float* __restrict__ bhh1,
    u64* bxo0, u64* bxo1,
    unsigned* rflag, unsigned* xflag, u64* tflag, float* h1l)
{
  __shared__ SMem sm;
  const int bid = blockIdx.x;
  // pair p occupies bids with constant bid%8 -> one XCD under round-robin
  // dispatch (heuristic; verified by handshake + smoke test, else fallback).
  const int p  = (bid & 7) * 2 + ((bid >> 3) & 1);
  const int mi = bid >> 4;                       // 0..31: 0-15 L0, 16-31 L1
  u64* r0 = bxo0 + (size_t)p * 8192;
  u64* r1 = bxo1 + (size_t)p * 8192;
  if (mi < 16) {
    lstm_body<0>(&sm, x, Wih0, Whh0, bih0, bhh0, r0, r0,
                 rflag, xflag, tflag, nullptr, p, mi);
  } else {
    lstm_body<1>(&sm, nullptr, Wih1, Whh1, bih1, bhh1, r0, r1,
                 rflag, xflag, tflag, h1l, p, mi - 16);
  }
}

__global__ void fc_kernel(const float* __restrict__ h1l, const float* __restrict__ Wfc,
                          float* __restrict__ out) {
  __shared__ float hs[H_];
  const int b = blockIdx.x, o = threadIdx.x;
  hs[o]       = h1l[b * H_ + o];
  hs[o + 128] = h1l[b * H_ + o + 128];
  __syncthreads();
  float acc = 0.f;
  #pragma unroll 8
  for (int u = 0; u < H_; u += 4) {
    float4 wv = *(const float4*)&Wfc[o * H_ + u];
    acc += wv.x * hs[u] + wv.y * hs[u + 1] + wv.z * hs[u + 2] + wv.w * hs[u + 3];
  }
  out[b * OUTD + o] = acc;
}

extern "C" void kernel_launch(void* const* d_in, const int* in_sizes, int n_in,
                              void* d_out, int out_size, void* d_ws, size_t ws_size,
                              hipStream_t stream) {
  const float* x    = (const float*)d_in[0];
  const float* Wih0 = (const float*)d_in[1];
  const float* Whh0 = (const float*)d_in[2];
  const float* bih0 = (const float*)d_in[3];
  const float* bhh0 = (const float*)d_in[4];
  const float* Wih1 = (const float*)d_in[5];
  const float* Whh1 = (const float*)d_in[6];
  const float* bih1 = (const float*)d_in[7];
  const float* bhh1 = (const float*)d_in[8];
  const float* Wfc  = (const float*)d_in[9];

  // ws: bxo0 1MiB | bxo1 1MiB | tflag 4KiB | rflag 16KiB | xflag 4KiB | h1l 256KiB
  u64*      bxo0  = (u64*)d_ws;                       // 16 pairs * 2 * 4096
  u64*      bxo1  = bxo0 + 131072;
  u64*      tflag = bxo1 + 131072;                    // 16*32 u64
  unsigned* rflag = (unsigned*)(tflag + 512);         // 16*256
  unsigned* xflag = rflag + 4096;                     // 16*64
  float*    h1l   = (float*)(xflag + 1024);           // 256*256

  // tflag/rflag/xflag must start 0 (0xAA poison would spoof the >= checks;
  // data tags / tokens / marker nibbles use equality, poison-proof).
  hipMemsetAsync(tflag, 0, 512 * 8 + (4096 + 1024) * 4, stream);

  lstm_fused<<<512, 256, 0, stream>>>(x, Wih0, Whh0, bih0, bhh0,
                                      Wih1, Whh1, bih1, bhh1,
                                      bxo0, bxo1, rflag, xflag, tflag, h1l);
  fc_kernel<<<256, 128, 0, stream>>>(h1l, Wfc, (float*)d_out);
}